// Round 8
// baseline (210.879 us; speedup 1.0000x reference)
//
#include <hip/hip_runtime.h>
#include <hip/hip_bf16.h>

// StochasticEnsemble: hard-routed 8-expert MLP.
// Round 8: occupancy fix — the round-7 plateau was grid starvation (456
// blocks = 1.78/CU). gemm2: 128x64 tiles -> 912 blocks, 3 blocks/CU (48 KB
// dbuf LDS), wave-specialized staging (waves 0-1: B f32->bf16 repack, waves
// 2-3: A b128 copy). gemm1: 128x32 tiles -> 608 blocks, 4 blocks/CU.
// Distance-1 prefetch, 1 barrier/iter, XOR-chunk LDS (0 conflicts measured).

#define BATCH 2048
#define ZD 128
#define HID 1024
#define OUTD 3072
#define NEXP 8
#define MAXTF 24          // max 128-row M-tiles

typedef short bf16x8 __attribute__((ext_vector_type(8)));   // 8 bf16 = 4 VGPRs
typedef float f32x4 __attribute__((ext_vector_type(4)));

// ---- workspace byte layout (ws_size = 384 MiB) ----
// 0        counts[8]
// 64       ntl[1]
// 128      texp[24]
// 256      perm[3072]               -> ends 12544
// 12544    bucket[8*2048]           -> ends 78080
// 78080    zb bf16 [2048*128]       -> ends 602368
// 602368   Hb bf16 [3072*1024]      -> ends 6893824

__global__ __launch_bounds__(256) void route_kernel(const float* __restrict__ z,
                                                    __hip_bfloat16* __restrict__ zb,
                                                    int* counts, int* bucket) {
    __shared__ int lcnt[NEXP];
    __shared__ int gbase[NEXP];
    int t = threadIdx.x;
    if (t < NEXP) lcnt[t] = 0;
    __syncthreads();

    int s = blockIdx.x * 32 + (t >> 3);          // sample
    int li = t & 7;                               // lane-in-sample
    const float* zp = z + (size_t)s * ZD + li * 16;
    float sum = 0.f;
    union { bf16x8 v8; __hip_bfloat16 h[8]; } u0, u1;
#pragma unroll
    for (int i = 0; i < 4; i++) {
        float4 v = ((const float4*)zp)[i];
        sum += floorf(fabsf(v.x) * 1000.0f) + floorf(fabsf(v.y) * 1000.0f) +
               floorf(fabsf(v.z) * 1000.0f) + floorf(fabsf(v.w) * 1000.0f);
        __hip_bfloat16* dst = (i < 2) ? &u0.h[i * 4] : &u1.h[(i - 2) * 4];
        dst[0] = __float2bfloat16(v.x);
        dst[1] = __float2bfloat16(v.y);
        dst[2] = __float2bfloat16(v.z);
        dst[3] = __float2bfloat16(v.w);
    }
    bf16x8* zo = (bf16x8*)(zb + (size_t)s * ZD + li * 16);
    zo[0] = u0.v8;
    zo[1] = u1.v8;

    sum += __shfl_down(sum, 4);
    sum += __shfl_down(sum, 2);
    sum += __shfl_down(sum, 1);
    int e = 0, lpos = 0;
    if (li == 0) {
        e = ((int)sum) & 7;
        lpos = atomicAdd(&lcnt[e], 1);
    }
    __syncthreads();
    if (t < NEXP) gbase[t] = atomicAdd(&counts[t], lcnt[t]);
    __syncthreads();
    if (li == 0) bucket[e * BATCH + gbase[e] + lpos] = s;
}

__global__ void scan_kernel(const int* __restrict__ counts, int* ntl,
                            int* texp, int* perm, const int* __restrict__ bucket) {
    __shared__ int soff[NEXP + 1];
    __shared__ int scnt[NEXP];
    if (threadIdx.x == 0) {
        int o = 0;
        for (int e = 0; e < NEXP; e++) {
            scnt[e] = counts[e];
            soff[e] = o;
            o += (scnt[e] + 127) & ~127;
        }
        soff[NEXP] = o;
        *ntl = o / 128;
    }
    __syncthreads();
    int total = soff[NEXP];
    for (int r = threadIdx.x; r < total; r += blockDim.x) {
        int e = 0;
        while (r >= soff[e + 1]) e++;
        int i = r - soff[e];
        perm[r] = (i < scnt[e]) ? bucket[e * BATCH + i] : -1;
        if ((r & 127) == 0) texp[r / 128] = e;
    }
}

// ---------------- gemm1: 128m x 32n, BK=64, K=128 (2 iters) ----------------
// Waves 2-3 stage A (zb gather, 8 chunks/thread); wave 0 stages B (f32->bf16
// repack, 4 chunks/thread); wave 1 idles in staging. LDS XOR-chunk layout.
__global__ __launch_bounds__(256, 4) void gemm1_fast(
    const __hip_bfloat16* __restrict__ zb, const float* __restrict__ W1,
    const float* __restrict__ b1, const int* __restrict__ ntl,
    const int* __restrict__ texp, const int* __restrict__ perm,
    __hip_bfloat16* __restrict__ H) {
    int mt = blockIdx.y;
    if (mt >= *ntl) return;
    int e = texp[mt];
    int n0 = blockIdx.x * 32;

    __shared__ __align__(16) __hip_bfloat16 As[2][128 * 64];   // 2 x 16 KB
    __shared__ __align__(16) __hip_bfloat16 Bs[2][32 * 64];    // 2 x 4 KB
    __shared__ int rows_s[128];

    int tid = threadIdx.x;
    if (tid < 128) rows_s[tid] = perm[mt * 128 + tid];
    __syncthreads();

    int lane = tid & 63, wave = tid >> 6;
    int cc = lane & 15, q = lane >> 4;
    int mw = (wave >> 1) * 64, nw = (wave & 1) * 16;

    bool isB = (wave == 0);
    bool isA = (wave >= 2);
    // B staging (wave 0): 32n x 64k from W1 f32
    int bkc = tid & 7, bn = ((tid >> 3) & 7) * 4;
    const float* Bgf = W1 + (size_t)e * ZD * HID + (size_t)(bkc * 8) * HID + n0 + bn;
    int bwb[4];
#pragma unroll
    for (int j = 0; j < 4; j++)
        bwb[j] = ((bn + j) * 8 + (bkc ^ ((bn + j) & 7))) * 8;
    // A staging (waves 2-3): gathered zb rows, 8 chunks/thread
    int t2 = tid & 127;
    int sc = t2 & 7, rg = t2 >> 3;
    const __hip_bfloat16* Arp[8];
#pragma unroll
    for (int p = 0; p < 8; p++) {
        int r = rows_s[rg + 16 * p];
        if (r < 0) r = 0;
        Arp[p] = zb + (size_t)r * ZD + sc * 8;
    }
    int awb = rg * 64 + (sc ^ (rg & 7)) * 8;     // row rg+16p -> + p*1024

    int A0 = (mw + cc) * 64, B0 = (nw + cc) * 64;
    int X0 = (q ^ (cc & 7)) * 8, X1 = ((4 + q) ^ (cc & 7)) * 8;

    float bias = b1[(size_t)e * HID + n0 + nw + cc];

    f32x4 zero4 = {0.f, 0.f, 0.f, 0.f};
    f32x4 acc[4];
#pragma unroll
    for (int i = 0; i < 4; i++) acc[i] = zero4;

    float4 braw[8];
    bf16x8 ga[8];
    if (isB) {
#pragma unroll
        for (int i = 0; i < 8; i++) braw[i] = *(const float4*)(Bgf + (size_t)i * HID);
    } else if (isA) {
#pragma unroll
        for (int p = 0; p < 8; p++) ga[p] = *(const bf16x8*)(Arp[p]);
    }

    const int NIT = ZD / 64;   // 2
#pragma unroll
    for (int it = 0; it < NIT; ++it) {
        __hip_bfloat16* Ac = As[it & 1];
        __hip_bfloat16* Bc = Bs[it & 1];
        if (isB) {
            union { bf16x8 v8; __hip_bfloat16 h[8]; } gbv[4];
#pragma unroll
            for (int i = 0; i < 8; i++) {
                gbv[0].h[i] = __float2bfloat16(braw[i].x);
                gbv[1].h[i] = __float2bfloat16(braw[i].y);
                gbv[2].h[i] = __float2bfloat16(braw[i].z);
                gbv[3].h[i] = __float2bfloat16(braw[i].w);
            }
#pragma unroll
            for (int j = 0; j < 4; j++) *(bf16x8*)(Bc + bwb[j]) = gbv[j].v8;
        } else if (isA) {
#pragma unroll
            for (int p = 0; p < 8; p++) *(bf16x8*)(Ac + awb + p * 1024) = ga[p];
        }
        if (it + 1 < NIT) {
            int k1 = (it + 1) * 64;
            if (isB) {
#pragma unroll
                for (int i = 0; i < 8; i++)
                    braw[i] = *(const float4*)(Bgf + (size_t)(k1 + i) * HID);
            } else if (isA) {
#pragma unroll
                for (int p = 0; p < 8; p++) ga[p] = *(const bf16x8*)(Arp[p] + k1);
            }
        }
        __syncthreads();
#pragma unroll
        for (int kh = 0; kh < 2; ++kh) {
            int X = kh ? X1 : X0;
            bf16x8 af[4], bfr;
#pragma unroll
            for (int i = 0; i < 4; i++) af[i] = *(const bf16x8*)(Ac + A0 + i * 1024 + X);
            bfr = *(const bf16x8*)(Bc + B0 + X);
#pragma unroll
            for (int i = 0; i < 4; i++)
                acc[i] = __builtin_amdgcn_mfma_f32_16x16x32_bf16(af[i], bfr,
                                                                 acc[i], 0, 0, 0);
        }
    }
#pragma unroll
    for (int i = 0; i < 4; i++)
#pragma unroll
        for (int r = 0; r < 4; r++) {
            int m = mw + i * 16 + q * 4 + r;
            H[(size_t)(mt * 128 + m) * HID + n0 + nw + cc] =
                __float2bfloat16(fmaxf(acc[i][r] + bias, 0.f));
        }
}

// ---------------- gemm2: 128m x 64n, BK=64, K=1024 (16 iters) --------------
// Waves 0-1 stage B (f32->bf16 repack, 4 chunks/thread); waves 2-3 stage A
// (H is already permuted -> plain b128 copy, 8 chunks/thread).
__global__ __launch_bounds__(256, 3) void gemm2_fast(
    const __hip_bfloat16* __restrict__ H, const float* __restrict__ W2,
    const float* __restrict__ b2, const int* __restrict__ ntl,
    const int* __restrict__ texp, const int* __restrict__ perm,
    float* __restrict__ out) {
    int mt = blockIdx.y;
    if (mt >= *ntl) return;
    int e = texp[mt];
    int n0 = blockIdx.x * 64;

    __shared__ __align__(16) __hip_bfloat16 As[2][128 * 64];   // 2 x 16 KB
    __shared__ __align__(16) __hip_bfloat16 Bs[2][64 * 64];    // 2 x 8 KB
    __shared__ int rows_s[128];

    int tid = threadIdx.x;
    if (tid < 128) rows_s[tid] = perm[mt * 128 + tid];   // epilogue-only; many
                                                         // barriers intervene
    int lane = tid & 63, wave = tid >> 6;
    int cc = lane & 15, q = lane >> 4;
    int mw = (wave >> 1) * 64, nw = (wave & 1) * 32;

    bool isB = (wave < 2);
    // B staging (threads 0..127): 64n x 64k from W2 f32
    int bkc = tid & 7, bn = ((tid >> 3) & 15) * 4;
    const float* Bgf = W2 + (size_t)e * HID * OUTD + (size_t)(bkc * 8) * OUTD + n0 + bn;
    int bwb[4];
#pragma unroll
    for (int j = 0; j < 4; j++)
        bwb[j] = ((bn + j) * 8 + (bkc ^ ((bn + j) & 7))) * 8;
    // A staging (threads 128..255): 128m x 64k from H bf16 (k-contig)
    int t2 = tid & 127;
    int sc = t2 & 7, rg = t2 >> 3;
    const __hip_bfloat16* Ag = H + ((size_t)mt * 128 + rg) * HID + sc * 8;
    int awb = rg * 64 + (sc ^ (rg & 7)) * 8;     // row rg+16p -> + p*1024

    int A0 = (mw + cc) * 64, B0 = (nw + cc) * 64;
    int X0 = (q ^ (cc & 7)) * 8, X1 = ((4 + q) ^ (cc & 7)) * 8;

    float bias[2];
#pragma unroll
    for (int j = 0; j < 2; j++) bias[j] = b2[(size_t)e * OUTD + n0 + nw + j * 16 + cc];

    f32x4 zero4 = {0.f, 0.f, 0.f, 0.f};
    f32x4 acc[4][2];
#pragma unroll
    for (int i = 0; i < 4; i++)
#pragma unroll
        for (int j = 0; j < 2; j++) acc[i][j] = zero4;

    float4 braw[8];
    bf16x8 ga[8];
    if (isB) {
#pragma unroll
        for (int i = 0; i < 8; i++) braw[i] = *(const float4*)(Bgf + (size_t)i * OUTD);
    } else {
#pragma unroll
        for (int p = 0; p < 8; p++) ga[p] = *(const bf16x8*)(Ag + (size_t)p * 16 * HID);
    }

    const int NIT = HID / 64;   // 16
    for (int it = 0; it < NIT; ++it) {
        __hip_bfloat16* Ac = As[it & 1];
        __hip_bfloat16* Bc = Bs[it & 1];
        if (isB) {
            union { bf16x8 v8; __hip_bfloat16 h[8]; } gbv[4];
#pragma unroll
            for (int i = 0; i < 8; i++) {
                gbv[0].h[i] = __float2bfloat16(braw[i].x);
                gbv[1].h[i] = __float2bfloat16(braw[i].y);
                gbv[2].h[i] = __float2bfloat16(braw[i].z);
                gbv[3].h[i] = __float2bfloat16(braw[i].w);
            }
#pragma unroll
            for (int j = 0; j < 4; j++) *(bf16x8*)(Bc + bwb[j]) = gbv[j].v8;
        } else {
#pragma unroll
            for (int p = 0; p < 8; p++) *(bf16x8*)(Ac + awb + p * 1024) = ga[p];
        }
        if (it + 1 < NIT) {
            int k1 = (it + 1) * 64;
            if (isB) {
#pragma unroll
                for (int i = 0; i < 8; i++)
                    braw[i] = *(const float4*)(Bgf + (size_t)(k1 + i) * OUTD);
            } else {
#pragma unroll
                for (int p = 0; p < 8; p++)
                    ga[p] = *(const bf16x8*)(Ag + (size_t)p * 16 * HID + k1);
            }
        }
        __syncthreads();
#pragma unroll
        for (int kh = 0; kh < 2; ++kh) {
            int X = kh ? X1 : X0;
            bf16x8 af[4], bfr[2];
#pragma unroll
            for (int i = 0; i < 4; i++) af[i] = *(const bf16x8*)(Ac + A0 + i * 1024 + X);
#pragma unroll
            for (int j = 0; j < 2; j++) bfr[j] = *(const bf16x8*)(Bc + B0 + j * 1024 + X);
#pragma unroll
            for (int i = 0; i < 4; i++)
#pragma unroll
                for (int j = 0; j < 2; j++)
                    acc[i][j] = __builtin_amdgcn_mfma_f32_16x16x32_bf16(af[i], bfr[j],
                                                                        acc[i][j], 0, 0, 0);
        }
    }
#pragma unroll
    for (int i = 0; i < 4; i++)
#pragma unroll
        for (int r = 0; r < 4; r++) {
            int m = mw + i * 16 + q * 4 + r;
            int orow = rows_s[m];
            if (orow >= 0) {
                float* op = out + (size_t)orow * OUTD + n0 + nw + cc;
#pragma unroll
                for (int j = 0; j < 2; j++) op[j * 16] = acc[i][j][r] + bias[j];
            }
        }
}

extern "C" void kernel_launch(void* const* d_in, const int* in_sizes, int n_in,
                              void* d_out, int out_size, void* d_ws, size_t ws_size,
                              hipStream_t stream) {
    const float* z  = (const float*)d_in[0];
    const float* W1 = (const float*)d_in[1];
    const float* b1 = (const float*)d_in[2];
    const float* W2 = (const float*)d_in[3];
    const float* b2 = (const float*)d_in[4];
    float* out = (float*)d_out;

    char* ws = (char*)d_ws;
    int* counts = (int*)ws;
    int* ntl    = (int*)(ws + 64);
    int* texp   = (int*)(ws + 128);
    int* perm   = (int*)(ws + 256);
    int* bucket = (int*)(ws + 12544);
    __hip_bfloat16* zb  = (__hip_bfloat16*)(ws + 78080);
    __hip_bfloat16* Hb  = (__hip_bfloat16*)(ws + 602368);

    hipMemsetAsync(counts, 0, 64, stream);
    hipLaunchKernelGGL(route_kernel, dim3(BATCH / 32), dim3(256), 0, stream,
                       z, zb, counts, bucket);
    hipLaunchKernelGGL(scan_kernel, dim3(1), dim3(256), 0, stream,
                       counts, ntl, texp, perm, bucket);
    hipLaunchKernelGGL(gemm1_fast, dim3(HID / 32, MAXTF), dim3(256), 0, stream,
                       zb, W1, b1, ntl, texp, perm, Hb);
    hipLaunchKernelGGL(gemm2_fast, dim3(OUTD / 64, MAXTF), dim3(256), 0, stream,
                       Hb, W2, b2, ntl, texp, perm, out);
}

// Round 9
// 200.892 us; speedup vs baseline: 1.0497x; 1.0497x over previous
//
#include <hip/hip_runtime.h>
#include <hip/hip_bf16.h>

// StochasticEnsemble: hard-routed 8-expert MLP.
// Round 9: (a) gemm2 reverted to the round-6 measured optimum (128x128,
// BK=64, all-thread staging, distance-1 prefetch, 1 barrier/iter, 59.9 us);
// (b) gemm1 re-tiled 64x64 -> ~608 blocks (was 152; 0.6 blocks/CU was the
// starvation), 32 KB dbuf LDS -> 4 blocks/CU. Wave-specialized staging from
// round 8 abandoned: it halved MFMA-per-barrier density and regressed.

#define BATCH 2048
#define ZD 128
#define HID 1024
#define OUTD 3072
#define NEXP 8
#define MAXTF 24          // max 128-row M-tiles

typedef short bf16x8 __attribute__((ext_vector_type(8)));   // 8 bf16 = 4 VGPRs
typedef float f32x4 __attribute__((ext_vector_type(4)));

// ---- workspace byte layout (ws_size = 384 MiB) ----
// 0        counts[8]
// 64       ntl[1]
// 128      texp[24]
// 256      perm[3072]               -> ends 12544
// 12544    bucket[8*2048]           -> ends 78080
// 78080    zb bf16 [2048*128]       -> ends 602368
// 602368   Hb bf16 [3072*1024]      -> ends 6893824

__global__ __launch_bounds__(256) void route_kernel(const float* __restrict__ z,
                                                    __hip_bfloat16* __restrict__ zb,
                                                    int* counts, int* bucket) {
    __shared__ int lcnt[NEXP];
    __shared__ int gbase[NEXP];
    int t = threadIdx.x;
    if (t < NEXP) lcnt[t] = 0;
    __syncthreads();

    int s = blockIdx.x * 32 + (t >> 3);          // sample
    int li = t & 7;                               // lane-in-sample
    const float* zp = z + (size_t)s * ZD + li * 16;
    float sum = 0.f;
    union { bf16x8 v8; __hip_bfloat16 h[8]; } u0, u1;
#pragma unroll
    for (int i = 0; i < 4; i++) {
        float4 v = ((const float4*)zp)[i];
        sum += floorf(fabsf(v.x) * 1000.0f) + floorf(fabsf(v.y) * 1000.0f) +
               floorf(fabsf(v.z) * 1000.0f) + floorf(fabsf(v.w) * 1000.0f);
        __hip_bfloat16* dst = (i < 2) ? &u0.h[i * 4] : &u1.h[(i - 2) * 4];
        dst[0] = __float2bfloat16(v.x);
        dst[1] = __float2bfloat16(v.y);
        dst[2] = __float2bfloat16(v.z);
        dst[3] = __float2bfloat16(v.w);
    }
    bf16x8* zo = (bf16x8*)(zb + (size_t)s * ZD + li * 16);
    zo[0] = u0.v8;
    zo[1] = u1.v8;

    sum += __shfl_down(sum, 4);
    sum += __shfl_down(sum, 2);
    sum += __shfl_down(sum, 1);
    int e = 0, lpos = 0;
    if (li == 0) {
        e = ((int)sum) & 7;
        lpos = atomicAdd(&lcnt[e], 1);
    }
    __syncthreads();
    if (t < NEXP) gbase[t] = atomicAdd(&counts[t], lcnt[t]);
    __syncthreads();
    if (li == 0) bucket[e * BATCH + gbase[e] + lpos] = s;
}

__global__ void scan_kernel(const int* __restrict__ counts, int* ntl,
                            int* texp, int* perm, const int* __restrict__ bucket) {
    __shared__ int soff[NEXP + 1];
    __shared__ int scnt[NEXP];
    if (threadIdx.x == 0) {
        int o = 0;
        for (int e = 0; e < NEXP; e++) {
            scnt[e] = counts[e];
            soff[e] = o;
            o += (scnt[e] + 127) & ~127;
        }
        soff[NEXP] = o;
        *ntl = o / 128;
    }
    __syncthreads();
    int total = soff[NEXP];
    for (int r = threadIdx.x; r < total; r += blockDim.x) {
        int e = 0;
        while (r >= soff[e + 1]) e++;
        int i = r - soff[e];
        perm[r] = (i < scnt[e]) ? bucket[e * BATCH + i] : -1;
        if ((r & 127) == 0) texp[r / 128] = e;
    }
}

// ---------------- gemm1: 64m x 64n, BK=64, K=128 (2 iters) ----------------
// ~608 blocks. All-thread staging; dbuf; 1 barrier/iter; XOR-chunk LDS.
__global__ __launch_bounds__(256, 4) void gemm1_fast(
    const __hip_bfloat16* __restrict__ zb, const float* __restrict__ W1,
    const float* __restrict__ b1, const int* __restrict__ ntl,
    const int* __restrict__ texp, const int* __restrict__ perm,
    __hip_bfloat16* __restrict__ H) {
    int mt = blockIdx.y;                 // 64-row tile index
    if (mt >= 2 * (*ntl)) return;
    int e = texp[mt >> 1];
    int n0 = blockIdx.x * 64;

    __shared__ __align__(16) __hip_bfloat16 As[2][64 * 64];   // 2 x 8 KB
    __shared__ __align__(16) __hip_bfloat16 Bs[2][64 * 64];   // 2 x 8 KB

    int tid = threadIdx.x;
    int lane = tid & 63, wave = tid >> 6;
    int cc = lane & 15, q = lane >> 4;
    int mw = (wave >> 1) * 32, nw = (wave & 1) * 32;

    // A staging: thread t covers rows rg and rg+32, k-chunk sc
    int sc = tid & 7, rg = tid >> 3;     // rg 0..31
    int r0 = perm[mt * 64 + rg];      if (r0 < 0) r0 = 0;
    int r1 = perm[mt * 64 + rg + 32]; if (r1 < 0) r1 = 0;
    const __hip_bfloat16* Ap0 = zb + (size_t)r0 * ZD + sc * 8;
    const __hip_bfloat16* Ap1 = zb + (size_t)r1 * ZD + sc * 8;
    int awb = rg * 64 + (sc ^ (rg & 7)) * 8;   // row rg+32 -> +2048, same xor

    // B staging: bkc = k-chunk, 2 n per thread (float2 loads, 64B segments)
    int bkc = tid & 7, bn2 = (tid >> 3) * 2;   // bn2 0..62
    const float* Bgf = W1 + (size_t)e * ZD * HID + (size_t)(bkc * 8) * HID + n0 + bn2;
    int bwb[2];
#pragma unroll
    for (int j = 0; j < 2; j++)
        bwb[j] = ((bn2 + j) * 8 + (bkc ^ ((bn2 + j) & 7))) * 8;

    int A0 = (mw + cc) * 64, B0 = (nw + cc) * 64;
    int X0 = (q ^ (cc & 7)) * 8, X1 = ((4 + q) ^ (cc & 7)) * 8;

    float bias[2];
#pragma unroll
    for (int j = 0; j < 2; j++) bias[j] = b1[(size_t)e * HID + n0 + nw + j * 16 + cc];

    f32x4 zero4 = {0.f, 0.f, 0.f, 0.f};
    f32x4 acc[2][2];
#pragma unroll
    for (int i = 0; i < 2; i++)
#pragma unroll
        for (int j = 0; j < 2; j++) acc[i][j] = zero4;

    bf16x8 ga0 = *(const bf16x8*)Ap0;
    bf16x8 ga1 = *(const bf16x8*)Ap1;
    float2 braw[8];
#pragma unroll
    for (int i = 0; i < 8; i++) braw[i] = *(const float2*)(Bgf + (size_t)i * HID);

#pragma unroll
    for (int it = 0; it < 2; ++it) {
        __hip_bfloat16* Ac = As[it];
        __hip_bfloat16* Bc = Bs[it];
        union { bf16x8 v8; __hip_bfloat16 h[8]; } gbv[2];
#pragma unroll
        for (int i = 0; i < 8; i++) {
            gbv[0].h[i] = __float2bfloat16(braw[i].x);
            gbv[1].h[i] = __float2bfloat16(braw[i].y);
        }
        *(bf16x8*)(Ac + awb) = ga0;
        *(bf16x8*)(Ac + awb + 2048) = ga1;
#pragma unroll
        for (int j = 0; j < 2; j++) *(bf16x8*)(Bc + bwb[j]) = gbv[j].v8;
        if (it == 0) {
            ga0 = *(const bf16x8*)(Ap0 + 64);
            ga1 = *(const bf16x8*)(Ap1 + 64);
#pragma unroll
            for (int i = 0; i < 8; i++)
                braw[i] = *(const float2*)(Bgf + (size_t)(64 + i) * HID);
        }
        __syncthreads();
#pragma unroll
        for (int kh = 0; kh < 2; ++kh) {
            int X = kh ? X1 : X0;
            bf16x8 af[2], bfr[2];
#pragma unroll
            for (int i = 0; i < 2; i++) af[i] = *(const bf16x8*)(Ac + A0 + i * 1024 + X);
#pragma unroll
            for (int j = 0; j < 2; j++) bfr[j] = *(const bf16x8*)(Bc + B0 + j * 1024 + X);
#pragma unroll
            for (int i = 0; i < 2; i++)
#pragma unroll
                for (int j = 0; j < 2; j++)
                    acc[i][j] = __builtin_amdgcn_mfma_f32_16x16x32_bf16(af[i], bfr[j],
                                                                        acc[i][j], 0, 0, 0);
        }
    }
#pragma unroll
    for (int i = 0; i < 2; i++)
#pragma unroll
        for (int r = 0; r < 4; r++) {
            int m = mw + i * 16 + q * 4 + r;
            __hip_bfloat16* hp = H + (size_t)(mt * 64 + m) * HID + n0 + nw + cc;
#pragma unroll
            for (int j = 0; j < 2; j++)
                hp[j * 16] = __float2bfloat16(fmaxf(acc[i][j][r] + bias[j], 0.f));
        }
}

// ---------------- gemm2: round-6 measured optimum ----------------
// 128x128, BK=64, all-thread staging, raw-f32 register prefetch (distance 1),
// convert deferred past the MFMA phase, ONE barrier per iter, 2 LDS buffers.
__global__ __launch_bounds__(256, 2) void gemm2_fast(
    const __hip_bfloat16* __restrict__ H, const float* __restrict__ W2,
    const float* __restrict__ b2, const int* __restrict__ ntl,
    const int* __restrict__ texp, const int* __restrict__ perm,
    float* __restrict__ out) {
    int mt = blockIdx.y;
    if (mt >= *ntl) return;
    int e = texp[mt];
    int n0 = blockIdx.x * 128;

    __shared__ __align__(16) __hip_bfloat16 As[2][128 * 64];   // 2 x 16 KB
    __shared__ __align__(16) __hip_bfloat16 Bs[2][128 * 64];   // 2 x 16 KB
    __shared__ int rows_s[128];

    int tid = threadIdx.x;
    if (tid < 128) rows_s[tid] = perm[mt * 128 + tid];

    int lane = tid & 63, wave = tid >> 6;
    int cc = lane & 15, q = lane >> 4;
    int mw = (wave >> 1) * 64, nw = (wave & 1) * 64;

    int sr = tid >> 3, sc = tid & 7;
    int awbase = sr * 64 + (sc ^ (sr & 7)) * 8;     // + p*2048
    const __hip_bfloat16* Ag = H + ((size_t)mt * 128 + sr) * HID + sc * 8;
    int bkc = tid & 7, bn = (tid >> 3) * 4;
    const float* Bgf = W2 + (size_t)e * HID * OUTD + (size_t)(bkc * 8) * OUTD + n0 + bn;
    int bwb[4];
#pragma unroll
    for (int j = 0; j < 4; j++)
        bwb[j] = (bn + j) * 64 + ((bkc ^ ((bn + j) & 7))) * 8;

    int A0 = (mw + cc) * 64, B0 = (nw + cc) * 64;
    int X0 = (q ^ (cc & 7)) * 8, X1 = ((4 + q) ^ (cc & 7)) * 8;

    float bias[4];
#pragma unroll
    for (int j = 0; j < 4; j++) bias[j] = b2[(size_t)e * OUTD + n0 + nw + j * 16 + cc];

    f32x4 zero4 = {0.f, 0.f, 0.f, 0.f};
    f32x4 acc[4][4];
#pragma unroll
    for (int i = 0; i < 4; i++)
#pragma unroll
        for (int j = 0; j < 4; j++) acc[i][j] = zero4;

    bf16x8 ga[4];
    float4 braw[8];
#pragma unroll
    for (int p = 0; p < 4; p++) ga[p] = *(const bf16x8*)(Ag + (size_t)p * 32 * HID);
#pragma unroll
    for (int i = 0; i < 8; i++) braw[i] = *(const float4*)(Bgf + (size_t)i * OUTD);

    const int NIT = HID / 64;   // 16
    for (int it = 0; it < NIT; ++it) {
        __hip_bfloat16* Ac = As[it & 1];
        __hip_bfloat16* Bc = Bs[it & 1];
        union { bf16x8 v8; __hip_bfloat16 h[8]; } gb[4];
#pragma unroll
        for (int i = 0; i < 8; i++) {
            gb[0].h[i] = __float2bfloat16(braw[i].x);
            gb[1].h[i] = __float2bfloat16(braw[i].y);
            gb[2].h[i] = __float2bfloat16(braw[i].z);
            gb[3].h[i] = __float2bfloat16(braw[i].w);
        }
#pragma unroll
        for (int p = 0; p < 4; p++) *(bf16x8*)(Ac + awbase + p * 2048) = ga[p];
#pragma unroll
        for (int j = 0; j < 4; j++) *(bf16x8*)(Bc + bwb[j]) = gb[j].v8;
        if (it + 1 < NIT) {
            int k1 = (it + 1) * 64;
#pragma unroll
            for (int p = 0; p < 4; p++)
                ga[p] = *(const bf16x8*)(Ag + (size_t)p * 32 * HID + k1);
#pragma unroll
            for (int i = 0; i < 8; i++)
                braw[i] = *(const float4*)(Bgf + (size_t)(k1 + i) * OUTD);
        }
        __syncthreads();
#pragma unroll
        for (int kh = 0; kh < 2; ++kh) {
            int X = kh ? X1 : X0;
            bf16x8 af[4], bfr[4];
#pragma unroll
            for (int i = 0; i < 4; i++) af[i] = *(const bf16x8*)(Ac + A0 + i * 1024 + X);
#pragma unroll
            for (int j = 0; j < 4; j++) bfr[j] = *(const bf16x8*)(Bc + B0 + j * 1024 + X);
#pragma unroll
            for (int i = 0; i < 4; i++)
#pragma unroll
                for (int j = 0; j < 4; j++)
                    acc[i][j] = __builtin_amdgcn_mfma_f32_16x16x32_bf16(af[i], bfr[j],
                                                                        acc[i][j], 0, 0, 0);
        }
    }
#pragma unroll
    for (int i = 0; i < 4; i++)
#pragma unroll
        for (int r = 0; r < 4; r++) {
            int m = mw + i * 16 + q * 4 + r;
            int orow = rows_s[m];
            if (orow >= 0) {
                float* op = out + (size_t)orow * OUTD + n0 + nw + cc;
#pragma unroll
                for (int j = 0; j < 4; j++) op[j * 16] = acc[i][j][r] + bias[j];
            }
        }
}

extern "C" void kernel_launch(void* const* d_in, const int* in_sizes, int n_in,
                              void* d_out, int out_size, void* d_ws, size_t ws_size,
                              hipStream_t stream) {
    const float* z  = (const float*)d_in[0];
    const float* W1 = (const float*)d_in[1];
    const float* b1 = (const float*)d_in[2];
    const float* W2 = (const float*)d_in[3];
    const float* b2 = (const float*)d_in[4];
    float* out = (float*)d_out;

    char* ws = (char*)d_ws;
    int* counts = (int*)ws;
    int* ntl    = (int*)(ws + 64);
    int* texp   = (int*)(ws + 128);
    int* perm   = (int*)(ws + 256);
    int* bucket = (int*)(ws + 12544);
    __hip_bfloat16* zb  = (__hip_bfloat16*)(ws + 78080);
    __hip_bfloat16* Hb  = (__hip_bfloat16*)(ws + 602368);

    hipMemsetAsync(counts, 0, 64, stream);
    hipLaunchKernelGGL(route_kernel, dim3(BATCH / 32), dim3(256), 0, stream,
                       z, zb, counts, bucket);
    hipLaunchKernelGGL(scan_kernel, dim3(1), dim3(256), 0, stream,
                       counts, ntl, texp, perm, bucket);
    hipLaunchKernelGGL(gemm1_fast, dim3(HID / 64, 2 * MAXTF), dim3(256), 0, stream,
                       zb, W1, b1, ntl, texp, perm, Hb);
    hipLaunchKernelGGL(gemm2_fast, dim3(OUTD / 128, MAXTF), dim3(256), 0, stream,
                       Hb, W2, b2, ntl, texp, perm, out);
}